// Round 11
// baseline (969.433 us; speedup 1.0000x reference)
//
#include <hip/hip_runtime.h>
#include <hip/hip_bf16.h>

// Problem: B=8192 rows, D=4096. 3 layers of relu(l2norm(h) @ W^T + b).
// ROUND 11: TLP. 256x256/8-wave/1-block-per-CU (R6) -> 128x128/4-wave
// blocks, 64 KiB LDS => TWO blocks per CU. Every prior attempt to shrink
// the ~1980cyc/tile sync residue INSIDE one block failed (R7/R8 cover
// collapse, R9 VALU, R10 spill); with 2 independent barrier domains per
// CU, one block's gate stalls hide under the other's MFMA (m97/m114
// mechanism). Same verified 2-phase schedule, XOR swizzle, coalesced
// staging as R6 -- only the partitioning changes.
//
// Per tile t (buf = t&1):
//  ph0: read bF(t) x8 [pre-BAR] | BAR | stage A(t+1)+B(t+1) -> other buf |
//       GATE [bF+aX] | window aY(t) x4 | MFMA16(acc[0..1][*], aX)
//  ph1: VMW(0) | BAR | GATE [aY] | window aX(t+1) x4 | MFMA16(acc[2..3], aY)
// WAR (stage @ph0(t) post-BAR into buf holding A/B(t-1)): aY(t-1) drained
//  at GATE(ph1,t-1), aX(t-1) at GATE(ph0,t-1), bF(t-1) at GATE(ph0,t-1);
//  all precede BAR(ph0,t) in every wave's program order, and the stager
//  passed BAR(ph0,t) => all waves executed those gates. SAFE (formal).
// RAW: aX(t+1) read after VMW(0)+BAR(ph1,t) which retire/publish the
//  ph0(t) stages; bF(t)/aY(t) retired at VMW(0)(ph1,t-1)+BAR. Prologue
//  drains VMW(0) (R7 lesson: no counted waits across independent issues).
// Shallow drain cover (~600cyc) is intentional: the co-resident block
// hides it -- that is the experiment.

#define NROWS 8192
#define DIM   4096

typedef __bf16 bf16x8 __attribute__((ext_vector_type(8)));
typedef float  f32x4  __attribute__((ext_vector_type(4)));

__device__ static inline short f2bf(float f) {
  __hip_bfloat16 h = __float2bfloat16(f);
  return __builtin_bit_cast(short, h);
}

#define BARRIER() do { asm volatile("" ::: "memory"); \
                       __builtin_amdgcn_s_barrier();  \
                       asm volatile("" ::: "memory"); } while (0)
#define GATE()   do { asm volatile("s_waitcnt lgkmcnt(0)" ::: "memory"); \
                      __builtin_amdgcn_sched_barrier(0); } while (0)
#define VMW(N)   do { asm volatile("s_waitcnt vmcnt(" #N ")" ::: "memory"); \
                      __builtin_amdgcn_sched_barrier(0); } while (0)

__global__ __launch_bounds__(256, 2)
void gemm128_bias_relu(const short* __restrict__ A,
                       const short* __restrict__ Bw,
                       const float* __restrict__ bias,
                       float* __restrict__ C,
                       int M, int N, int K)
{
  __shared__ short lds[4][8192];   // [buf*2+op][128 rows * 64 bf16] = 64 KiB

  // XCD-aware swizzle (bijective: grid % 8 == 0 here)
  int bid = blockIdx.x;
  const int nwg = gridDim.x;
  if ((nwg & 7) == 0) { const int cpx = nwg >> 3; bid = (bid & 7) * cpx + (bid >> 3); }
  const int nbn  = N >> 7;
  const int brow = (bid / nbn) << 7;
  const int bcol = (bid % nbn) << 7;

  const int lane = threadIdx.x & 63;
  const int wid  = threadIdx.x >> 6;   // 0..3
  const int wr   = wid >> 1;           // 0..1 : 64-row band
  const int wc   = wid & 1;            // 0..1 : 64-col band

  f32x4 acc[4][4] = {};

  const size_t rowK = (size_t)K * 2;   // bytes per global row
  char* const  ldsB = (char*)&lds[0][0];

  // ---- staging addressing (coalesced, source pre-swizzled) ----
  const int r8  = lane >> 3;
  const int kcs = (lane & 7) ^ r8;
  const char* AgL = (const char*)A  + (size_t)(brow + r8) * rowK + (size_t)kcs * 16;
  const char* BgL = (const char*)Bw + (size_t)(bcol + r8) * rowK + (size_t)kcs * 16;
  int rbo[4], rbb[4];
#pragma unroll
  for (int i = 0; i < 4; ++i) {
    const int rb = wid * 8 + i * 32;   // 4 waves x 4 segs x 8 rows = 128
    rbo[i] = rb * (int)rowK;
    rbb[i] = rb * 128;
  }
  // stage one 128-row operand tile: 4 x global_load_lds(16B) per thread
  auto stage = [&](const char* gsrc, char* lb, int tile) {
    const char* gp = gsrc + ((size_t)tile << 7);
#pragma unroll
    for (int s = 0; s < 4; ++s)
      __builtin_amdgcn_global_load_lds(
          (const __attribute__((address_space(1))) void*)(gp + rbo[s]),
          (__attribute__((address_space(3))) void*)(lb + rbb[s]), 16, 0, 0);
  };

  // ---- fragment read addressing (swizzled: phys kc = kc ^ (row&7)) ----
  const int l15  = lane & 15;
  const int xlo  = ((lane >> 4) ^ (lane & 3)) * 16;
  const int b2   = (lane >> 2) & 1;
  const int k64[2] = { b2 << 6, (1 - b2) << 6 };
  const int abase = (wr * 64 + l15) * 128 + xlo;
  const int bbase = (wc * 64 + l15) * 128 + xlo;

  const int NT = K >> 6;

  bf16x8 aX[2][2], aY[2][2], bF[4][2];

#define LOAD_A2(DST, PTR, I0)                                                \
  _Pragma("unroll")                                                          \
  for (int ii = 0; ii < 2; ++ii)                                             \
    _Pragma("unroll")                                                        \
    for (int ks = 0; ks < 2; ++ks)                                           \
      DST[ii][ks] = *reinterpret_cast<const bf16x8*>(                        \
          (PTR) + abase + ((I0) + ii) * 2048 + k64[ks]);

// ks outer: same-acc revisit distance = 8 instructions
#define MFMA16(I0, AF)                                                       \
  _Pragma("unroll")                                                          \
  for (int ks = 0; ks < 2; ++ks)                                             \
    _Pragma("unroll")                                                        \
    for (int ii = 0; ii < 2; ++ii)                                           \
      _Pragma("unroll")                                                      \
      for (int j = 0; j < 4; ++j)                                            \
        acc[(I0) + ii][j] = __builtin_amdgcn_mfma_f32_16x16x32_bf16(         \
            AF[ii][ks], bF[j][ks], acc[(I0) + ii][j], 0, 0, 0);

  // ---- prologue: stage A(0),B(0); full drain; publish; pre-read aX(0) ----
  stage(AgL, ldsB,         0);
  stage(BgL, ldsB + 16384, 0);
  VMW(0);
  BARRIER();
  LOAD_A2(aX, ldsB, 0)

  for (int t = 0; t < NT; ++t) {
    const int cur = t & 1;
    const char* At = ldsB + cur * 32768;
    const char* Bt = At + 16384;
    char*       An = ldsB + (cur ^ 1) * 32768;

    // ---- phase 0 ----
#pragma unroll
    for (int j = 0; j < 4; ++j)
#pragma unroll
      for (int ks = 0; ks < 2; ++ks)
        bF[j][ks] = *reinterpret_cast<const bf16x8*>(Bt + bbase + j * 2048 + k64[ks]);
    BARRIER();
    if (t + 1 < NT) { stage(AgL, An, t + 1); stage(BgL, An + 16384, t + 1); }
    GATE();                              // bF + aX(t) ready
    LOAD_A2(aY, At, 2)                   // window: overlaps MFMA
    __builtin_amdgcn_s_setprio(1);
    MFMA16(0, aX)
    __builtin_amdgcn_s_setprio(0);

    // ---- phase 1 ----
    VMW(0);                              // land A/B(t+1); other block hides
    BARRIER();
    GATE();                              // aY ready
    if (t + 1 < NT) { LOAD_A2(aX, An, 0) }
    __builtin_amdgcn_s_setprio(1);
    MFMA16(2, aY)
    __builtin_amdgcn_s_setprio(0);
  }
#undef MFMA16
#undef LOAD_A2

  // epilogue: C/D layout col = lane&15, row = (lane>>4)*4 + reg
  float bv[4];
#pragma unroll
  for (int j = 0; j < 4; ++j)
    bv[j] = bias[bcol + wc * 64 + j * 16 + (lane & 15)];
#pragma unroll
  for (int i = 0; i < 4; ++i) {
    const int rbase = brow + wr * 64 + i * 16 + ((lane >> 4) << 2);
#pragma unroll
    for (int j = 0; j < 4; ++j) {
      const int col = bcol + wc * 64 + j * 16 + (lane & 15);
#pragma unroll
      for (int r = 0; r < 4; ++r) {
        const float v = acc[i][j][r] + bv[j];
        C[(size_t)(rbase + r) * N + col] = v > 0.f ? v : 0.f;
      }
    }
  }
}

// ---------------------------------------------------------------------------
// Row L2-normalize (fp32 in) -> bf16 out. One block (256 thr) per row of 4096.
// ---------------------------------------------------------------------------
__global__ __launch_bounds__(256)
void rownorm_bf16(const float* __restrict__ in, short* __restrict__ out)
{
  const int row = blockIdx.x;
  const int t0  = threadIdx.x;
  const float4* inr = (const float4*)(in + (size_t)row * DIM);

  float4 v[4];
  float ss = 0.f;
#pragma unroll
  for (int t = 0; t < 4; ++t) {
    v[t] = inr[t0 + t * 256];
    ss += v[t].x * v[t].x + v[t].y * v[t].y + v[t].z * v[t].z + v[t].w * v[t].w;
  }
#pragma unroll
  for (int off = 32; off > 0; off >>= 1)
    ss += __shfl_down(ss, off, 64);

  __shared__ float wss[4];
  if ((t0 & 63) == 0) wss[t0 >> 6] = ss;
  __syncthreads();
  const float tot   = wss[0] + wss[1] + wss[2] + wss[3];
  const float scale = 1.f / fmaxf(sqrtf(tot), 1e-12f);  // F.normalize eps

  short4* outr = (short4*)(out + (size_t)row * DIM);
#pragma unroll
  for (int t = 0; t < 4; ++t) {
    short4 o;
    o.x = f2bf(v[t].x * scale);
    o.y = f2bf(v[t].y * scale);
    o.z = f2bf(v[t].z * scale);
    o.w = f2bf(v[t].w * scale);
    outr[t0 + t * 256] = o;
  }
}

// ---------------------------------------------------------------------------
// fp32 -> bf16 bulk cast (for W), vectorized, grid-stride.
// ---------------------------------------------------------------------------
__global__ __launch_bounds__(256)
void cast_bf16(const float* __restrict__ in, short* __restrict__ out, int n4)
{
  int i = blockIdx.x * 256 + threadIdx.x;
  const int stride = gridDim.x * 256;
  for (; i < n4; i += stride) {
    const float4 v = ((const float4*)in)[i];
    short4 o;
    o.x = f2bf(v.x);
    o.y = f2bf(v.y);
    o.z = f2bf(v.z);
    o.w = f2bf(v.w);
    ((short4*)out)[i] = o;
  }
}

extern "C" void kernel_launch(void* const* d_in, const int* in_sizes, int n_in,
                              void* d_out, int out_size, void* d_ws, size_t ws_size,
                              hipStream_t stream) {
  const float* x = (const float*)d_in[0];
  const float* W[3]    = { (const float*)d_in[1], (const float*)d_in[3], (const float*)d_in[5] };
  const float* bias[3] = { (const float*)d_in[2], (const float*)d_in[4], (const float*)d_in[6] };
  float* out = (float*)d_out;

  // workspace layout: hn bf16 [8192][4096] (64 MiB) | Wb bf16 [4096][4096] (32 MiB)
  short* hn = (short*)d_ws;
  short* Wb = (short*)((char*)d_ws + (size_t)NROWS * DIM * 2);

  const size_t layer_elems = (size_t)NROWS * DIM;
  const float* hin = x;

  for (int L = 0; L < 3; ++L) {
    cast_bf16<<<2048, 256, 0, stream>>>(W[L], Wb, DIM * DIM / 4);
    rownorm_bf16<<<NROWS, 256, 0, stream>>>(hin, hn);
    gemm128_bias_relu<<<(NROWS / 128) * (DIM / 128), 256, 0, stream>>>(
        hn, Wb, bias[L], out + (size_t)L * layer_elems, NROWS, DIM, DIM);
    hin = out + (size_t)L * layer_elems;
  }
}

// Round 12
// 840.680 us; speedup vs baseline: 1.1532x; 1.1532x over previous
//
#include <hip/hip_runtime.h>
#include <hip/hip_bf16.h>

// Problem: B=8192 rows, D=4096. 3 layers of relu(l2norm(h) @ W^T + b).
// ROUND 12: GEMM K-loop = R6 VERBATIM (best verified: 230us/GEMM, 55.4%
// MfmaUtil; 5 structural attacks on its residue all failed with known
// causes). New: row-norm FUSED via commutation -- relu(norm(h)W^T+b) =
// relu(s_r (hW^T) + b), s_r = 1/max(||h_r||,eps). Producing GEMM epilogue
// writes bf16(h) + atomically accumulates per-row sum-of-squares; consuming
// GEMM scales its accumulator by s_r. Kills the 192MiB rownorm pass for
// layers 1-2. Layer 0: castrow kernel (cast x->bf16 + direct row SS).
// Workspace 160MiB (hn ping-pong) -- launcher falls back to the old
// separate-rownorm path if ws_size is insufficient.

#define NROWS 8192
#define DIM   4096

typedef __bf16 bf16x8 __attribute__((ext_vector_type(8)));
typedef float  f32x4  __attribute__((ext_vector_type(4)));

__device__ static inline short f2bf(float f) {
  __hip_bfloat16 h = __float2bfloat16(f);
  return __builtin_bit_cast(short, h);
}

#define BARRIER() do { asm volatile("" ::: "memory"); \
                       __builtin_amdgcn_s_barrier();  \
                       asm volatile("" ::: "memory"); } while (0)
#define GATE()   do { asm volatile("s_waitcnt lgkmcnt(0)" ::: "memory"); \
                      __builtin_amdgcn_sched_barrier(0); } while (0)
#define VMW(N)   do { asm volatile("s_waitcnt vmcnt(" #N ")" ::: "memory"); \
                      __builtin_amdgcn_sched_barrier(0); } while (0)

// ---------------------------------------------------------------------------
// C[M,N] = relu(sIn_r * (A[M,K](bf16) . Bw[N,K](bf16)^T) + bias[N]), fp32.
// If hnOut: also write bf16(C) and atomicAdd per-row sum(C^2) into ssOut.
// K-loop identical to R6 (2 phases/tile, XOR-swizzled LDS, gload_lds).
// ---------------------------------------------------------------------------
__global__ __launch_bounds__(512, 2)
void gemm256_bias_relu(const short* __restrict__ A,
                       const short* __restrict__ Bw,
                       const float* __restrict__ bias,
                       const float* __restrict__ ssIn,   // may be null -> s=1
                       float* __restrict__ C,
                       float* __restrict__ ssOut,        // used if hnOut
                       short* __restrict__ hnOut,        // may be null
                       int M, int N, int K)
{
  __shared__ short lds[4][16384];   // [buf*2+op][256 rows * 64 bf16] = 128 KiB

  // XCD-aware swizzle (bijective: grid % 8 == 0 here)
  int bid = blockIdx.x;
  const int nwg = gridDim.x;
  if ((nwg & 7) == 0) { const int cpx = nwg >> 3; bid = (bid & 7) * cpx + (bid >> 3); }
  const int nbn  = N >> 8;
  const int brow = (bid / nbn) << 8;
  const int bcol = (bid % nbn) << 8;

  const int lane = threadIdx.x & 63;
  const int wid  = __builtin_amdgcn_readfirstlane(threadIdx.x >> 6);  // uniform
  const int wr   = wid >> 2;           // 0..1 : 128-row band
  const int wc   = wid & 3;            // 0..3 : 64-col band

  float bv[4];
#pragma unroll
  for (int j = 0; j < 4; ++j)
    bv[j] = bias[bcol + wc * 64 + j * 16 + (lane & 15)];

  f32x4 acc[8][4] = {};

  const size_t rowK = (size_t)K * 2;   // bytes per global row
  char* const  ldsB = (char*)&lds[0][0];

  // ---- staging addressing (coalesced, source pre-swizzled) ----
  const int r8  = lane >> 3;
  const int kcs = (lane & 7) ^ r8;
  const char* AgL = (const char*)A  + (size_t)(brow + r8) * rowK + (size_t)kcs * 16;
  const char* BgL = (const char*)Bw + (size_t)(bcol + r8) * rowK + (size_t)kcs * 16;
  int rbo[4], rbb[4];                  // wave-uniform (wid-derived) -> SGPR
#pragma unroll
  for (int i = 0; i < 4; ++i) {
    const int rb = wid * 8 + i * 64;
    rbo[i] = rb * (int)rowK;
    rbb[i] = rb * 128;
  }

  auto stage_half = [&](int parity, int op, int h, int tile) {
    const char* gp = (op ? BgL : AgL) + ((size_t)tile << 7);
    char* lb = ldsB + (parity * 2 + op) * 32768;
#pragma unroll
    for (int s = 0; s < 2; ++s) {
      const int idx = h * 2 + s;
      __builtin_amdgcn_global_load_lds(
          (const __attribute__((address_space(1))) void*)(gp + rbo[idx]),
          (__attribute__((address_space(3))) void*)(lb + rbb[idx]), 16, 0, 0);
    }
  };

  // ---- fragment read addressing (swizzled: phys kc = kc ^ (row&7)) ----
  const int l15  = lane & 15;
  const int xlo  = ((lane >> 4) ^ (lane & 3)) * 16;
  const int b2   = (lane >> 2) & 1;
  const int k64[2] = { b2 << 6, (1 - b2) << 6 };
  const int abase = (wr * 128 + l15) * 128 + xlo;
  const int bbase = (wc * 64  + l15) * 128 + xlo;

  const int NT = K >> 6;

  bf16x8 aX[4][2], aY[4][2], bF[4][2];

#define LOAD_FRAG(DST, PTR, BASE, I0)                                        \
  _Pragma("unroll")                                                          \
  for (int ii = 0; ii < 4; ++ii)                                             \
    _Pragma("unroll")                                                        \
    for (int ks = 0; ks < 2; ++ks)                                           \
      DST[ii][ks] = *reinterpret_cast<const bf16x8*>(                        \
          (PTR) + (BASE) + ((I0) + ii) * 2048 + k64[ks]);

// ks outer: same-acc revisit distance = 16 instructions
#define MFMA16(I0, AF)                                                       \
  _Pragma("unroll")                                                          \
  for (int ks = 0; ks < 2; ++ks)                                             \
    _Pragma("unroll")                                                        \
    for (int ii = 0; ii < 4; ++ii)                                           \
      _Pragma("unroll")                                                      \
      for (int j = 0; j < 4; ++j)                                            \
        acc[(I0) + ii][j] = __builtin_amdgcn_mfma_f32_16x16x32_bf16(         \
            AF[ii][ks], bF[j][ks], acc[(I0) + ii][j], 0, 0, 0);

  // ---- prologue: stage A0,B0,B1; full drain (order-independent, R7
  //      lesson); publish; pre-read aX(0) ----
  stage_half(0, 0, 0, 0); stage_half(0, 0, 1, 0);
  stage_half(0, 1, 0, 0); stage_half(0, 1, 1, 0);
  if (NT > 1) { stage_half(1, 1, 0, 1); stage_half(1, 1, 1, 1); }
  VMW(0);
  BARRIER();
  LOAD_FRAG(aX, ldsB, abase, 0)

  for (int t = 0; t < NT; ++t) {
    const int cur = t & 1, nxt = cur ^ 1;
    const char* At = ldsB + (cur * 2 + 0) * 32768;
    const char* Bt = ldsB + (cur * 2 + 1) * 32768;
    const char* An = ldsB + (nxt * 2 + 0) * 32768;

    // ---- phase 0 ----
    if (t + 1 < NT) { stage_half(nxt, 0, 0, t + 1); stage_half(nxt, 0, 1, t + 1); }
    LOAD_FRAG(bF, Bt, bbase, 0)
    BARRIER();
    GATE();                              // bF + aX ready
    LOAD_FRAG(aY, At, abase, 4)          // overlaps MFMA below
    __builtin_amdgcn_s_setprio(1);
    MFMA16(0, aX)
    __builtin_amdgcn_s_setprio(0);

    // ---- phase 1 ----
    VMW(0);                              // A(t+1),B(t+1) land
    BARRIER();
    GATE();                              // aY ready
    if (t + 2 < NT) { stage_half(cur, 1, 0, t + 2); stage_half(cur, 1, 1, t + 2); }
    if (t + 1 < NT) { LOAD_FRAG(aX, An, abase, 0) }   // next tile's aX
    __builtin_amdgcn_s_setprio(1);
    MFMA16(4, aY)
    __builtin_amdgcn_s_setprio(0);
  }
#undef MFMA16
#undef LOAD_FRAG

  // ---- epilogue: scale by s_r, bias, relu, write C; optionally write
  //      bf16 h to hnOut and accumulate row sum-of-squares into ssOut ----
  const bool aux = (hnOut != nullptr);
#pragma unroll
  for (int i = 0; i < 8; ++i) {
    const int rbase = brow + wr * 128 + i * 16 + ((lane >> 4) << 2);
#pragma unroll
    for (int r = 0; r < 4; ++r) {
      const int row = rbase + r;
      const float s = ssIn ? (1.f / fmaxf(sqrtf(ssIn[row]), 1e-12f)) : 1.f;
      float ssq = 0.f;
#pragma unroll
      for (int j = 0; j < 4; ++j) {
        const int col = bcol + wc * 64 + j * 16 + l15;
        float v = fmaf(acc[i][j][r], s, bv[j]);
        v = v > 0.f ? v : 0.f;
        C[(size_t)row * N + col] = v;
        if (aux) {
          hnOut[(size_t)row * N + col] = f2bf(v);
          ssq = fmaf(v, v, ssq);
        }
      }
      if (aux) {
        // sum over the 16 lanes (l15) sharing this row -> 64-col partial
        ssq += __shfl_xor(ssq, 1, 64);
        ssq += __shfl_xor(ssq, 2, 64);
        ssq += __shfl_xor(ssq, 4, 64);
        ssq += __shfl_xor(ssq, 8, 64);
        if (l15 == 0) atomicAdd(ssOut + row, ssq);
      }
    }
  }
}

// ---------------------------------------------------------------------------
// Layer-0 prep: cast x (fp32) -> bf16 UNNORMALIZED, write row SS to ss0
// directly (one block per row), and zero ss1/ss2 (first 64 blocks).
// ---------------------------------------------------------------------------
__global__ __launch_bounds__(256)
void castrow_bf16(const float* __restrict__ in, short* __restrict__ out,
                  float* __restrict__ ss0, float* __restrict__ ss1,
                  float* __restrict__ ss2)
{
  const int row = blockIdx.x;
  const int t0  = threadIdx.x;
  const float4* inr = (const float4*)(in + (size_t)row * DIM);

  float4 v[4];
  float ss = 0.f;
#pragma unroll
  for (int t = 0; t < 4; ++t) {
    v[t] = inr[t0 + t * 256];
    ss += v[t].x * v[t].x + v[t].y * v[t].y + v[t].z * v[t].z + v[t].w * v[t].w;
  }
#pragma unroll
  for (int off = 32; off > 0; off >>= 1)
    ss += __shfl_down(ss, off, 64);

  __shared__ float wss[4];
  if ((t0 & 63) == 0) wss[t0 >> 6] = ss;
  __syncthreads();
  if (t0 == 0) ss0[row] = wss[0] + wss[1] + wss[2] + wss[3];

  short4* outr = (short4*)(out + (size_t)row * DIM);
#pragma unroll
  for (int t = 0; t < 4; ++t) {
    short4 o;
    o.x = f2bf(v[t].x);
    o.y = f2bf(v[t].y);
    o.z = f2bf(v[t].z);
    o.w = f2bf(v[t].w);
    outr[t0 + t * 256] = o;
  }

  if (row < 64) {                      // zero ss1/ss2 (8192 floats each)
    if (t0 < 128) ss1[row * 128 + t0] = 0.f;
    else          ss2[row * 128 + (t0 - 128)] = 0.f;
  }
}

// ---------------------------------------------------------------------------
// Fallback path: normalizing rownorm (fp32 in -> normalized bf16 out).
// ---------------------------------------------------------------------------
__global__ __launch_bounds__(256)
void rownorm_bf16(const float* __restrict__ in, short* __restrict__ out)
{
  const int row = blockIdx.x;
  const int t0  = threadIdx.x;
  const float4* inr = (const float4*)(in + (size_t)row * DIM);

  float4 v[4];
  float ss = 0.f;
#pragma unroll
  for (int t = 0; t < 4; ++t) {
    v[t] = inr[t0 + t * 256];
    ss += v[t].x * v[t].x + v[t].y * v[t].y + v[t].z * v[t].z + v[t].w * v[t].w;
  }
#pragma unroll
  for (int off = 32; off > 0; off >>= 1)
    ss += __shfl_down(ss, off, 64);

  __shared__ float wss[4];
  if ((t0 & 63) == 0) wss[t0 >> 6] = ss;
  __syncthreads();
  const float tot   = wss[0] + wss[1] + wss[2] + wss[3];
  const float scale = 1.f / fmaxf(sqrtf(tot), 1e-12f);  // F.normalize eps

  short4* outr = (short4*)(out + (size_t)row * DIM);
#pragma unroll
  for (int t = 0; t < 4; ++t) {
    short4 o;
    o.x = f2bf(v[t].x * scale);
    o.y = f2bf(v[t].y * scale);
    o.z = f2bf(v[t].z * scale);
    o.w = f2bf(v[t].w * scale);
    outr[t0 + t * 256] = o;
  }
}

// ---------------------------------------------------------------------------
// fp32 -> bf16 bulk cast (for W), vectorized, grid-stride.
// ---------------------------------------------------------------------------
__global__ __launch_bounds__(256)
void cast_bf16(const float* __restrict__ in, short* __restrict__ out, int n4)
{
  int i = blockIdx.x * 256 + threadIdx.x;
  const int stride = gridDim.x * 256;
  for (; i < n4; i += stride) {
    const float4 v = ((const float4*)in)[i];
    short4 o;
    o.x = f2bf(v.x);
    o.y = f2bf(v.y);
    o.z = f2bf(v.z);
    o.w = f2bf(v.w);
    ((short4*)out)[i] = o;
  }
}

extern "C" void kernel_launch(void* const* d_in, const int* in_sizes, int n_in,
                              void* d_out, int out_size, void* d_ws, size_t ws_size,
                              hipStream_t stream) {
  const float* x = (const float*)d_in[0];
  const float* W[3]    = { (const float*)d_in[1], (const float*)d_in[3], (const float*)d_in[5] };
  const float* bias[3] = { (const float*)d_in[2], (const float*)d_in[4], (const float*)d_in[6] };
  float* out = (float*)d_out;

  const size_t layer_elems = (size_t)NROWS * DIM;
  const size_t hnB = layer_elems * 2;              // 64 MiB
  const size_t needed = hnB * 2 + (size_t)DIM * DIM * 2 + 3 * NROWS * 4;
  const int ngrid = (NROWS / 256) * (DIM / 256);   // 512

  if (ws_size >= needed) {
    // fused path: hn ping-pong + Wb + ss[3]
    short* hn0 = (short*)d_ws;
    short* hn1 = (short*)((char*)d_ws + hnB);
    short* Wb  = (short*)((char*)d_ws + 2 * hnB);
    float* ss0 = (float*)((char*)d_ws + 2 * hnB + (size_t)DIM * DIM * 2);
    float* ss1 = ss0 + NROWS;
    float* ss2 = ss1 + NROWS;

    cast_bf16<<<2048, 256, 0, stream>>>(W[0], Wb, DIM * DIM / 4);
    castrow_bf16<<<NROWS, 256, 0, stream>>>(x, hn0, ss0, ss1, ss2);
    gemm256_bias_relu<<<ngrid, 512, 0, stream>>>(
        hn0, Wb, bias[0], ss0, out, ss1, hn1, NROWS, DIM, DIM);
    cast_bf16<<<2048, 256, 0, stream>>>(W[1], Wb, DIM * DIM / 4);
    gemm256_bias_relu<<<ngrid, 512, 0, stream>>>(
        hn1, Wb, bias[1], ss1, out + layer_elems, ss2, hn0, NROWS, DIM, DIM);
    cast_bf16<<<2048, 256, 0, stream>>>(W[2], Wb, DIM * DIM / 4);
    gemm256_bias_relu<<<ngrid, 512, 0, stream>>>(
        hn0, Wb, bias[2], ss2, out + 2 * layer_elems, nullptr, nullptr,
        NROWS, DIM, DIM);
  } else {
    // fallback: original separate-rownorm path (96 MiB workspace)
    short* hn = (short*)d_ws;
    short* Wb = (short*)((char*)d_ws + hnB);
    const float* hin = x;
    for (int L = 0; L < 3; ++L) {
      cast_bf16<<<2048, 256, 0, stream>>>(W[L], Wb, DIM * DIM / 4);
      rownorm_bf16<<<NROWS, 256, 0, stream>>>(hin, hn);
      gemm256_bias_relu<<<ngrid, 512, 0, stream>>>(
          hn, Wb, bias[L], nullptr, out + (size_t)L * layer_elems,
          nullptr, nullptr, NROWS, DIM, DIM);
      hin = out + (size_t)L * layer_elems;
    }
  }
}

// Round 13
// 779.338 us; speedup vs baseline: 1.2439x; 1.0787x over previous
//
#include <hip/hip_runtime.h>
#include <hip/hip_bf16.h>

// Problem: B=8192 rows, D=4096. 3 layers of relu(l2norm(h) @ W^T + b).
// FINAL = ROUND 6 VERBATIM (best verified: 779 us total, 230 us/GEMM,
// MfmaUtil 55.4%). GEMM: 256x256 tile, BK=64, 8 waves, 16x16x32 MFMA,
// 2 phases/K-tile, XOR-swizzled LDS (0 bank conflicts), coalesced
// global_load_lds staging, raw barriers, setprio around MFMA clusters.
// Subsequent experiments all regressed with identified causes:
//  R5  32x32x16 MFMA        -> 2.5e7 LDS bank-conflict cycles
//  R7/8 B direct from L2    -> prefetch-cover collapse (257us)
//  R9  runtime 5-buf rotate -> VALU +4.5% (244us)
//  R10 period-6 unroll      -> scratch spill, WRITE +187MB (295us)
//  R11 128^2 tiles for TLP  -> FETCH 3.2x, HBM-pressure (327us)
//  R12 norm fusion          -> producer-side epilogue +46us/GEMM (840us)
// The ~1830cyc/tile sync residue is structural at 1 block/CU on this
// register/LDS budget; every depth>=2 pipeline route hits a resource wall.

#define NROWS 8192
#define DIM   4096

typedef __bf16 bf16x8 __attribute__((ext_vector_type(8)));
typedef float  f32x4  __attribute__((ext_vector_type(4)));

__device__ static inline short f2bf(float f) {
  __hip_bfloat16 h = __float2bfloat16(f);
  return __builtin_bit_cast(short, h);
}

#define BARRIER() do { asm volatile("" ::: "memory"); \
                       __builtin_amdgcn_s_barrier();  \
                       asm volatile("" ::: "memory"); } while (0)
#define GATE()   do { asm volatile("s_waitcnt lgkmcnt(0)" ::: "memory"); \
                      __builtin_amdgcn_sched_barrier(0); } while (0)

__global__ __launch_bounds__(512, 2)
void gemm256_bias_relu(const short* __restrict__ A,
                       const short* __restrict__ Bw,
                       const float* __restrict__ bias,
                       float* __restrict__ C,
                       int M, int N, int K)
{
  __shared__ short lds[4][16384];   // [buf*2+op][256 rows * 64 bf16] = 128 KiB

  // XCD-aware swizzle (bijective: grid % 8 == 0 here)
  int bid = blockIdx.x;
  const int nwg = gridDim.x;
  if ((nwg & 7) == 0) { const int cpx = nwg >> 3; bid = (bid & 7) * cpx + (bid >> 3); }
  const int nbn  = N >> 8;
  const int brow = (bid / nbn) << 8;
  const int bcol = (bid % nbn) << 8;

  const int lane = threadIdx.x & 63;
  const int wid  = __builtin_amdgcn_readfirstlane(threadIdx.x >> 6);  // uniform
  const int wr   = wid >> 2;           // 0..1 : 128-row output band
  const int wc   = wid & 3;            // 0..3 : 64-col output band

  float bv[4];
#pragma unroll
  for (int j = 0; j < 4; ++j)
    bv[j] = bias[bcol + wc * 64 + j * 16 + (lane & 15)];

  f32x4 acc[8][4] = {};

  const size_t rowK = (size_t)K * 2;   // bytes per global row
  char* const  ldsB = (char*)&lds[0][0];

  // ---- staging addressing (coalesced, source pre-swizzled) ----
  const int r8  = lane >> 3;
  const int kcs = (lane & 7) ^ r8;
  const char* AgL = (const char*)A  + (size_t)(brow + r8) * rowK + (size_t)kcs * 16;
  const char* BgL = (const char*)Bw + (size_t)(bcol + r8) * rowK + (size_t)kcs * 16;
  int rbo[4], rbb[4];                  // wave-uniform (wid-derived) -> SGPR
#pragma unroll
  for (int i = 0; i < 4; ++i) {
    const int rb = wid * 8 + i * 64;
    rbo[i] = rb * (int)rowK;
    rbb[i] = rb * 128;
  }

  // stage one full tile operand half: 2 x global_load_lds(16B) per thread
  auto stage_half = [&](int parity, int op, int h, int tile) {
    const char* gp = (op ? BgL : AgL) + ((size_t)tile << 7);
    char* lb = ldsB + (parity * 2 + op) * 32768;
#pragma unroll
    for (int s = 0; s < 2; ++s) {
      const int idx = h * 2 + s;
      __builtin_amdgcn_global_load_lds(
          (const __attribute__((address_space(1))) void*)(gp + rbo[idx]),
          (__attribute__((address_space(3))) void*)(lb + rbb[idx]), 16, 0, 0);
    }
  };

  // ---- fragment read addressing (swizzled: phys kc = kc ^ (row&7)) ----
  const int l15  = lane & 15;
  const int xlo  = ((lane >> 4) ^ (lane & 3)) * 16;
  const int b2   = (lane >> 2) & 1;
  const int k64[2] = { b2 << 6, (1 - b2) << 6 };
  const int abase = (wr * 128 + l15) * 128 + xlo;
  const int bbase = (wc * 64  + l15) * 128 + xlo;

  const int NT = K >> 6;

  bf16x8 aX[4][2], aY[4][2], bF[4][2];   // plain arrays; rewrites follow last use

#define LOAD_FRAG(DST, PTR, BASE, I0)                                        \
  _Pragma("unroll")                                                          \
  for (int ii = 0; ii < 4; ++ii)                                             \
    _Pragma("unroll")                                                        \
    for (int ks = 0; ks < 2; ++ks)                                           \
      DST[ii][ks] = *reinterpret_cast<const bf16x8*>(                        \
          (PTR) + (BASE) + ((I0) + ii) * 2048 + k64[ks]);

// ks outer: same-acc revisit distance = 16 instructions
#define MFMA16(I0, AF)                                                       \
  _Pragma("unroll")                                                          \
  for (int ks = 0; ks < 2; ++ks)                                             \
    _Pragma("unroll")                                                        \
    for (int ii = 0; ii < 4; ++ii)                                           \
      _Pragma("unroll")                                                      \
      for (int j = 0; j < 4; ++j)                                            \
        acc[(I0) + ii][j] = __builtin_amdgcn_mfma_f32_16x16x32_bf16(         \
            AF[ii][ks], bF[j][ks], acc[(I0) + ii][j], 0, 0, 0);

  // ---- prologue: stage A0,B0,B1; land A0,B0 (vmcnt(4): B1 stays in
  //      flight); publish; pre-read aX(0) ----
  stage_half(0, 0, 0, 0); stage_half(0, 0, 1, 0);
  stage_half(0, 1, 0, 0); stage_half(0, 1, 1, 0);
  if (NT > 1) { stage_half(1, 1, 0, 1); stage_half(1, 1, 1, 1); }
  if (NT > 1) asm volatile("s_waitcnt vmcnt(4)" ::: "memory");
  else        asm volatile("s_waitcnt vmcnt(0)" ::: "memory");
  BARRIER();
  LOAD_FRAG(aX, ldsB, abase, 0)        // drains at ph0's gate

  for (int t = 0; t < NT; ++t) {
    const int cur = t & 1, nxt = cur ^ 1;
    const char* At = ldsB + (cur * 2 + 0) * 32768;
    const char* Bt = ldsB + (cur * 2 + 1) * 32768;
    const char* An = ldsB + (nxt * 2 + 0) * 32768;

    // ---- phase 0 ----
    if (t + 1 < NT) { stage_half(nxt, 0, 0, t + 1); stage_half(nxt, 0, 1, t + 1); }
    LOAD_FRAG(bF, Bt, bbase, 0)
    BARRIER();
    GATE();                              // bF + aX ready
    LOAD_FRAG(aY, At, abase, 4)          // overlaps MFMA below
    __builtin_amdgcn_s_setprio(1);
    MFMA16(0, aX)
    __builtin_amdgcn_s_setprio(0);

    // ---- phase 1 ----
    asm volatile("s_waitcnt vmcnt(0)" ::: "memory");  // A(t+1),B(t+1) land
    BARRIER();
    GATE();                              // aY ready
    if (t + 2 < NT) { stage_half(cur, 1, 0, t + 2); stage_half(cur, 1, 1, t + 2); }
    if (t + 1 < NT) { LOAD_FRAG(aX, An, abase, 0) }   // next tile's aX
    __builtin_amdgcn_s_setprio(1);
    MFMA16(4, aY)
    __builtin_amdgcn_s_setprio(0);
  }
#undef MFMA16
#undef LOAD_FRAG

  // epilogue: C/D layout col = lane&15, row = (lane>>4)*4 + reg
#pragma unroll
  for (int i = 0; i < 8; ++i) {
    const int rbase = brow + wr * 128 + i * 16 + ((lane >> 4) << 2);
#pragma unroll
    for (int j = 0; j < 4; ++j) {
      const int col = bcol + wc * 64 + j * 16 + (lane & 15);
#pragma unroll
      for (int r = 0; r < 4; ++r) {
        const float v = acc[i][j][r] + bv[j];
        C[(size_t)(rbase + r) * N + col] = v > 0.f ? v : 0.f;
      }
    }
  }
}

// ---------------------------------------------------------------------------
// Row L2-normalize (fp32 in) -> bf16 out. One block (256 thr) per row of 4096.
// ---------------------------------------------------------------------------
__global__ __launch_bounds__(256)
void rownorm_bf16(const float* __restrict__ in, short* __restrict__ out)
{
  const int row = blockIdx.x;
  const int t0  = threadIdx.x;
  const float4* inr = (const float4*)(in + (size_t)row * DIM);

  float4 v[4];
  float ss = 0.f;
#pragma unroll
  for (int t = 0; t < 4; ++t) {
    v[t] = inr[t0 + t * 256];
    ss += v[t].x * v[t].x + v[t].y * v[t].y + v[t].z * v[t].z + v[t].w * v[t].w;
  }
#pragma unroll
  for (int off = 32; off > 0; off >>= 1)
    ss += __shfl_down(ss, off, 64);

  __shared__ float wss[4];
  if ((t0 & 63) == 0) wss[t0 >> 6] = ss;
  __syncthreads();
  const float tot   = wss[0] + wss[1] + wss[2] + wss[3];
  const float scale = 1.f / fmaxf(sqrtf(tot), 1e-12f);  // F.normalize eps

  short4* outr = (short4*)(out + (size_t)row * DIM);
#pragma unroll
  for (int t = 0; t < 4; ++t) {
    short4 o;
    o.x = f2bf(v[t].x * scale);
    o.y = f2bf(v[t].y * scale);
    o.z = f2bf(v[t].z * scale);
    o.w = f2bf(v[t].w * scale);
    outr[t0 + t * 256] = o;
  }
}

// ---------------------------------------------------------------------------
// fp32 -> bf16 bulk cast (for W), vectorized, grid-stride.
// ---------------------------------------------------------------------------
__global__ __launch_bounds__(256)
void cast_bf16(const float* __restrict__ in, short* __restrict__ out, int n4)
{
  int i = blockIdx.x * 256 + threadIdx.x;
  const int stride = gridDim.x * 256;
  for (; i < n4; i += stride) {
    const float4 v = ((const float4*)in)[i];
    short4 o;
    o.x = f2bf(v.x);
    o.y = f2bf(v.y);
    o.z = f2bf(v.z);
    o.w = f2bf(v.w);
    ((short4*)out)[i] = o;
  }
}

extern "C" void kernel_launch(void* const* d_in, const int* in_sizes, int n_in,
                              void* d_out, int out_size, void* d_ws, size_t ws_size,
                              hipStream_t stream) {
  const float* x = (const float*)d_in[0];
  const float* W[3]    = { (const float*)d_in[1], (const float*)d_in[3], (const float*)d_in[5] };
  const float* bias[3] = { (const float*)d_in[2], (const float*)d_in[4], (const float*)d_in[6] };
  float* out = (float*)d_out;

  // workspace layout: hn bf16 [8192][4096] (64 MiB) | Wb bf16 [4096][4096] (32 MiB)
  short* hn = (short*)d_ws;
  short* Wb = (short*)((char*)d_ws + (size_t)NROWS * DIM * 2);

  const size_t layer_elems = (size_t)NROWS * DIM;
  const float* hin = x;

  for (int L = 0; L < 3; ++L) {
    cast_bf16<<<2048, 256, 0, stream>>>(W[L], Wb, DIM * DIM / 4);
    rownorm_bf16<<<NROWS, 256, 0, stream>>>(hin, hn);
    gemm256_bias_relu<<<(NROWS / 256) * (DIM / 256), 512, 0, stream>>>(
        hn, Wb, bias[L], out + (size_t)L * layer_elems, NROWS, DIM, DIM);
    hin = out + (size_t)L * layer_elems;
  }
}